// Round 8
// baseline (157.278 us; speedup 1.0000x reference)
//
#include <hip/hip_runtime.h>

#define BATCH 4
#define LEN   1024
#define KNB   30
#define CH    128
#define EIN   434
#define KP    448      // padded K
#define KST   14       // k-steps of 32
#define ASTR  456      // A row stride in ushorts (228 words = 4 mod 32 banks)
#define CSTR  132      // C row stride in floats
#define AJS   20       // sAJ row stride in floats

typedef unsigned short ushort_t;
typedef __attribute__((ext_vector_type(8))) short bf16x8;
typedef __attribute__((ext_vector_type(4))) float f32x4;

// PAIRS atom indices: N=0, Ca=1, C=2, O=3, Cb=4
__constant__ int c_pa[24] = {0,2,3,4,1,1,1,1,0,0,0,4,4,3,0,2,3,4,2,3,4,2,3,2};
__constant__ int c_pb[24] = {0,2,3,4,0,2,3,4,2,3,4,2,3,2,1,1,1,1,0,0,0,4,4,3};

struct F3 { float x, y, z; };
__device__ __forceinline__ F3 f3sub(F3 a, F3 b){ return {a.x-b.x, a.y-b.y, a.z-b.z}; }
__device__ __forceinline__ F3 f3cross(F3 a, F3 b){
  return {a.y*b.z - a.z*b.y, a.z*b.x - a.x*b.z, a.x*b.y - a.y*b.x};
}
__device__ __forceinline__ float f3dot(F3 a, F3 b){ return a.x*b.x + a.y*b.y + a.z*b.z; }
__device__ __forceinline__ F3 f3norm(F3 a){
  float s2 = f3dot(a,a);
  float inv = (s2 > 0.f) ? __builtin_amdgcn_rsqf(s2) : 0.f;
  return {a.x*inv, a.y*inv, a.z*inv};
}
__device__ __forceinline__ float fsign(float x){ return (x > 0.f) ? 1.f : ((x < 0.f) ? -1.f : 0.f); }
__device__ __forceinline__ float clip1(float c){ return fminf(fmaxf(c, -1.f + 1e-7f), 1.f - 1e-7f); }

// cos(sign*acos(cd)) = cd ; sin(sign*acos(cd)) = sign*sqrt(1-cd^2)
__device__ __forceinline__ void dihedral_cs(F3 ua, F3 ub, F3 uc, float& c, float& s){
  F3 n0 = f3norm(f3cross(ua, ub));
  F3 n1 = f3norm(f3cross(ub, uc));
  float cd = clip1(f3dot(n0, n1));
  F3 v = f3norm(f3cross(n0, n1));
  c = cd;
  s = fsign(-f3dot(v, ub)) * sqrtf(1.f - cd*cd);
}

__device__ __forceinline__ ushort_t f2bf(float f){
  unsigned u = __float_as_uint(f);
  unsigned r = u + 0x7FFFu + ((u >> 16) & 1u);   // round-to-nearest-even
  return (ushort_t)(r >> 16);
}

// HW packed f32->bf16 (RNE): 1 inst per 2 elements
__device__ __forceinline__ unsigned cvt_pk(float a, float b){
  unsigned r;
  asm("v_cvt_pk_bf16_f32 %0, %1, %2" : "=v"(r) : "v"(a), "v"(b));
  return r;
}

// Column permutation: RBF pair p's 16 elems stored as two 8-halves at
// 16+p*8 and 216+p*8 (spreads phase-A b128 writes over all 8 bank-phases).
// Wfrag is packed with the same permutation so the GEMM is unchanged.
__device__ __forceinline__ int corig(int c){
  if (c < 16 || c >= 416) return c;
  int base = (c < 216) ? 16 : 216;
  int p = (c - base) >> 3, m = (c - base) & 7;
  return 16 + p*16 + m + ((c < 216) ? 0 : 8);
}

// Wave-wide u32 min via DPP (short dependency chain, 3 insts/step).
#define DPP_MIN_STEP(v, ctrl) do{                                            \
    unsigned t_ = (unsigned)__builtin_amdgcn_update_dpp(                     \
        (int)0xFFFFFFFF, (int)(v), (ctrl), 0xF, 0xF, false);                 \
    (v) = t_ < (v) ? t_ : (v);                                               \
  } while(0)
__device__ __forceinline__ unsigned wave_min_u32(unsigned v){
  DPP_MIN_STEP(v, 0x111);   // row_shr:1
  DPP_MIN_STEP(v, 0x112);   // row_shr:2
  DPP_MIN_STEP(v, 0x114);   // row_shr:4
  DPP_MIN_STEP(v, 0x118);   // row_shr:8
  DPP_MIN_STEP(v, 0x142);   // row_bcast:15
  DPP_MIN_STEP(v, 0x143);   // row_bcast:31
  return (unsigned)__builtin_amdgcn_readlane((int)v, 63);
}

// ---------------------------------------------------------------------------
// Blocks 0..15: per-node prep (Cb, frame Q, node feats, packed Ca).
// Blocks 16..43: pack W_edge into bf16 B-fragment order (with corig perm).
__global__ __launch_bounds__(256) void prep_kernel(
    const float* __restrict__ X, const float* __restrict__ mask,
    const float* __restrict__ We,
    float* __restrict__ wCb, float* __restrict__ wQ, float* __restrict__ wVn,
    float* __restrict__ wCa, ushort_t* __restrict__ Wfrag)
{
  if (blockIdx.x >= 16){
    int f = (blockIdx.x - 16)*256 + threadIdx.x;
    if (f >= 8*KST*64) return;
    int t = f / (KST*64);
    int s = (f / 64) % KST;
    int l = f & 63;
    int n  = t*16 + (l & 15);
    int k0 = s*32 + (l >> 4)*8;
    ushort_t v[8];
    #pragma unroll
    for (int j = 0; j < 8; ++j){
      int k = k0 + j;
      v[j] = (k < EIN) ? f2bf(We[(size_t)corig(k)*CH + n]) : (ushort_t)0;
    }
    ulong2* dst = (ulong2*)(Wfrag + (size_t)f*8);
    *dst = *(ulong2*)v;
    return;
  }

  int idx = blockIdx.x * 256 + threadIdx.x;
  int n = idx & (LEN - 1);
  const float* p = X + (size_t)idx * 12;
  const float4* p4 = (const float4*)p;
  float4 q0 = p4[0], q1 = p4[1], q2 = p4[2];
  F3 Na = {q0.x, q0.y, q0.z};
  F3 Ca = {q0.w, q1.x, q1.y};
  F3 Cc = {q1.z, q1.w, q2.x};
  F3 Oa = {q2.y, q2.z, q2.w};
  ((float4*)wCa)[idx] = make_float4(Ca.x, Ca.y, Ca.z, 0.f);
  F3 bv = f3sub(Ca, Na);
  F3 cv = f3sub(Cc, Ca);
  F3 av = f3cross(bv, cv);
  ((float4*)wCb)[idx] = make_float4(
    -0.58273431f*av.x + 0.56802827f*bv.x - 0.54067466f*cv.x + Ca.x,
    -0.58273431f*av.y + 0.56802827f*bv.y - 0.54067466f*cv.y + Ca.y,
    -0.58273431f*av.z + 0.56802827f*bv.z - 0.54067466f*cv.z + Ca.z, 0.f);

  F3 u0 = f3norm(bv);
  F3 u1 = f3norm(cv);

  float Q[9];
  if (n < LEN - 1){
    F3 b1 = f3norm(f3sub(u0, u1));
    F3 n0 = f3norm(f3cross(u0, u1));
    F3 r2 = f3cross(b1, n0);
    Q[0]=b1.x; Q[1]=b1.y; Q[2]=b1.z;
    Q[3]=n0.x; Q[4]=n0.y; Q[5]=n0.z;
    Q[6]=r2.x; Q[7]=r2.y; Q[8]=r2.z;
  } else {
    #pragma unroll
    for (int t = 0; t < 9; ++t) Q[t] = 0.f;
  }
  float4* wq4 = (float4*)(wQ + (size_t)idx*12);
  wq4[0] = make_float4(Q[0], Q[1], Q[2], Q[3]);
  wq4[1] = make_float4(Q[4], Q[5], Q[6], Q[7]);
  wq4[2] = make_float4(Q[8], 0.f, 0.f, 0.f);

  float m = mask[idx];
  bool hp = (n > 0), hn = (n < LEN - 1);
  F3 um1 = {0,0,0}, u2 = {0,0,0}, u3 = {0,0,0};
  if (hp){
    const float* pp = p - 12;
    F3 Cp = {pp[6], pp[7], pp[8]};
    um1 = f3norm(f3sub(Na, Cp));
  }
  if (hn){
    const float* pn = p + 12;
    F3 Nn  = {pn[0], pn[1], pn[2]};
    F3 Can = {pn[3], pn[4], pn[5]};
    u2 = f3norm(f3sub(Nn, Cc));
    u3 = f3norm(f3sub(Can, Nn));
  }
  float cD0=1.f,sD0=0.f, cD1=1.f,sD1=0.f, cD2=1.f,sD2=0.f;
  float cA0=1.f,sA0=0.f, cA1=1.f,sA1=0.f, cA2=1.f,sA2=0.f;
  if (hp){
    dihedral_cs(um1, u0, u1, cD0, sD0);
    cA0 = clip1(f3dot(um1, u0)); sA0 = sqrtf(1.f - cA0*cA0);
  }
  if (hn){
    dihedral_cs(u0, u1, u2, cD1, sD1);
    dihedral_cs(u1, u2, u3, cD2, sD2);
    cA1 = clip1(f3dot(u0, u1)); sA1 = sqrtf(1.f - cA1*cA1);
    cA2 = clip1(f3dot(u1, u2)); sA2 = sqrtf(1.f - cA2*cA2);
  }
  float vn[22];
  vn[0] = cD0*m; vn[1] = cD1*m; vn[2]  = cD2*m;
  vn[3] = sD0*m; vn[4] = sD1*m; vn[5]  = sD2*m;
  vn[6] = cA0*m; vn[7] = cA1*m; vn[8]  = cA2*m;
  vn[9] = sA0*m; vn[10]= sA1*m; vn[11] = sA2*m;
  F3 dxs[3];
  dxs[0] = {0.f, 0.f, 0.f};
  dxs[1] = f3sub(Cc, Na);
  dxs[2] = f3sub(Oa, Na);
  #pragma unroll
  for (int a = 0; a < 3; ++a){
    F3 dv = dxs[a];
    F3 du = { Q[0]*dv.x + Q[1]*dv.y + Q[2]*dv.z,
              Q[3]*dv.x + Q[4]*dv.y + Q[5]*dv.z,
              Q[6]*dv.x + Q[7]*dv.y + Q[8]*dv.z };
    F3 dn = f3norm(du);
    vn[12 + a*3 + 0] = dn.x * m;
    vn[12 + a*3 + 1] = dn.y * m;
    vn[12 + a*3 + 2] = dn.z * m;
  }
  vn[21] = m;
  #pragma unroll
  for (int t = 0; t < 22; ++t) wVn[(size_t)idx*22 + t] = vn[t];
}

// ---------------------------------------------------------------------------
// Wave-per-node top-30 (pure: writes only wIdx). Fast round: u32 DPP min on
// dist; unique-tie fast path via ballot; exact lax.top_k order via fallback
// index-min on genuine bitwise dist ties.
__global__ __launch_bounds__(256) void topk_kernel(
    const float* __restrict__ wCa, int* __restrict__ wIdx)
{
  int wid = threadIdx.x >> 6, l = threadIdx.x & 63;
  int bi = blockIdx.x*4 + wid;
  int b  = bi >> 10;
  const float4* Ca = (const float4*)wCa;
  float4 ci = Ca[bi];
  const float4* Cb = Ca + (size_t)b * LEN;

  unsigned D[16];
  #pragma unroll
  for (int t = 0; t < 16; ++t){
    int j = l + 64*t;
    float4 cj = Cb[j];
    float dx = ci.x - cj.x, dy = ci.y - cj.y, dz = ci.z - cj.z;
    D[t] = __float_as_uint(sqrtf(dx*dx + dy*dy + dz*dz + 1e-6f));
  }
  unsigned lmin = D[0]; unsigned jmin = (unsigned)l;
  #pragma unroll
  for (int t = 1; t < 16; ++t)
    if (D[t] < lmin){ lmin = D[t]; jmin = (unsigned)(l + 64*t); }

  for (int k = 0; k < KNB; ++k){
    unsigned dmin = wave_min_u32(lmin);
    unsigned long long tie = __ballot(lmin == dmin);
    bool iwin;
    unsigned jw;
    if (__popcll(tie) == 1ull){
      iwin = (lmin == dmin);           // unique dist -> that lane's jmin wins
      jw = jmin;
    } else {
      unsigned cand = (lmin == dmin) ? jmin : 0xFFFFFFFFu;
      jw = wave_min_u32(cand);         // min index among tied lanes
      iwin = (cand == jw);
    }
    if (iwin){
      wIdx[bi*KNB + k] = (int)jw;
      int tw = (int)(jw >> 6);
      #pragma unroll
      for (int t = 0; t < 16; ++t) if (t == tw) D[t] = 0xFFFFFFFFu;
      lmin = D[0]; jmin = (unsigned)l;
      #pragma unroll
      for (int t = 1; t < 16; ++t)
        if (D[t] < lmin){ lmin = D[t]; jmin = (unsigned)(l + 64*t); }
    }
  }
}

// ---------------------------------------------------------------------------
// Block per node, 512 threads / 8 waves (round-3 Phase-B structure).
// Gather-phase latency bubble absorbs: node-LN (wave 7) + outI (wave 4).
__global__ __launch_bounds__(512) void edge_kernel(
    const float* __restrict__ X, const float* __restrict__ mask,
    const int* __restrict__ resi, const int* __restrict__ chain,
    const float* __restrict__ Wp, const float* __restrict__ bp,
    const float* __restrict__ ge, const float* __restrict__ be,
    const float* __restrict__ wCb, const float* __restrict__ wQ,
    const int* __restrict__ wIdx, const float* __restrict__ wVn,
    const float* __restrict__ Wn,  const float* __restrict__ gn,
    const float* __restrict__ bn,  const ushort_t* __restrict__ Wfrag,
    float* __restrict__ outV, float* __restrict__ outE,
    float* __restrict__ outI)
{
  __shared__ __align__(16) ushort_t As[32*ASTR];   // 29184 B, reused as C (f32) later
  // sAJ row: [0..11]=X_j (N,Ca,C,O), [12..14]=Cb_j, [15]=pad, [16]=chain,
  //          [17]=maskJ, [18]=offI(as float), [19]=pad.
  __shared__ __align__(16) float sAJ[KNB][AJS];
  __shared__ __align__(16) float sAI[16];
  __shared__ __align__(16) float sQi[12];

  int bi  = blockIdx.x;
  int b   = bi >> 10;
  int tid = threadIdx.x;
  int w   = tid >> 6, l = tid & 63;

  // ---- gather phase: waves 0..3 gather; wave 4 outI; wave 7 node-LN ----
  float qj0=0.f,qj1=0.f,qj2=0.f,qj3=0.f,qj4=0.f,qj5=0.f,qj6=0.f,qj7=0.f,qj8=0.f;
  if (w == 0 && l < KNB){
    int j  = wIdx[bi*KNB + l];
    int gj = (b << 10) + j;
    const float4* pj4 = (const float4*)(X + (size_t)gj * 12);
    *(float4*)&sAJ[l][0] = pj4[0];
    *(float4*)&sAJ[l][4] = pj4[1];
    *(float4*)&sAJ[l][8] = pj4[2];
  } else if (w == 1 && l < KNB){
    int j  = wIdx[bi*KNB + l];
    int gj = (b << 10) + j;
    *(float4*)&sAJ[l][12] = ((const float4*)wCb)[gj];   // fills [12..15], [15]=0 pad
    sAJ[l][16] = (chain[bi] == chain[gj]) ? 1.f : 0.f;
    sAJ[l][17] = mask[gj];
    sAJ[l][18] = (float)(resi[bi] - resi[gj]);
  } else if (w == 2 && l < KNB){
    int j  = wIdx[bi*KNB + l];
    int gj = (b << 10) + j;
    const float4* q4 = (const float4*)(wQ + (size_t)gj * 12);
    float4 a = q4[0], bq = q4[1], cq = q4[2];
    qj0=a.x; qj1=a.y; qj2=a.z; qj3=a.w;
    qj4=bq.x; qj5=bq.y; qj6=bq.z; qj7=bq.w;
    qj8=cq.x;
  } else if (w == 3 && l == 0){
    const float4* pi4 = (const float4*)(X + (size_t)bi * 12);
    *(float4*)&sAI[0]  = pi4[0];
    *(float4*)&sAI[4]  = pi4[1];
    *(float4*)&sAI[8]  = pi4[2];
    *(float4*)&sAI[12] = ((const float4*)wCb)[bi];
  } else if (w == 3 && l == 1){
    const float4* q4 = (const float4*)(wQ + (size_t)bi * 12);
    *(float4*)&sQi[0] = q4[0];
    *(float4*)&sQi[4] = q4[1];
    *(float4*)&sQi[8] = q4[2];
  } else if (w == 4 && l < KNB){
    outI[(size_t)bi*KNB + l] = (float)wIdx[bi*KNB + l];
  } else if (w == 7){
    // node LN matmul in the gather latency bubble:
    // Vn = LN(vn_raw @ W_node) * g + b
    float x0 = 0.f, x1 = 0.f;
    #pragma unroll
    for (int r = 0; r < 22; ++r){
      float vr = wVn[(size_t)bi*22 + r];    // wave-uniform broadcast
      x0 = fmaf(vr, Wn[r*CH + l],      x0);
      x1 = fmaf(vr, Wn[r*CH + l + 64], x1);
    }
    float sum = x0 + x1;
    #pragma unroll
    for (int off = 1; off < 64; off <<= 1) sum += __shfl_xor(sum, off);
    float mu = sum * (1.f/128.f);
    float d0 = x0 - mu, d1 = x1 - mu;
    float vs = d0*d0 + d1*d1;
    #pragma unroll
    for (int off = 1; off < 64; off <<= 1) vs += __shfl_xor(vs, off);
    float inv = 1.f / sqrtf(vs * (1.f/128.f) + 1e-5f);
    outV[(size_t)bi*CH + l]      = d0*inv*gn[l]    + bn[l];
    outV[(size_t)bi*CH + l + 64] = d1*inv*gn[l+64] + bn[l+64];
  }
  // zero pad cols 434..447 of rows 0..29
  for (int e = tid; e < KNB*14; e += 512){
    int r = e / 14, c = EIN + (e % 14);
    As[r*ASTR + c] = 0;
  }
  __syncthreads();

  // ---- Phase A ----
  auto rbf_task = [&](int tau){
    int k = (int)(((unsigned)tau * 5243u) >> 17);   // tau/25
    int p = tau - k*25;
    // p==0 is the Ca-Ca pair (identical formula incl. the 1e-6 eps)
    int ai = (p == 0) ? 3 : c_pa[p-1]*3;
    int bj = (p == 0) ? 3 : c_pb[p-1]*3;
    float dx = sAI[ai+0] - sAJ[k][bj+0];
    float dy = sAI[ai+1] - sAJ[k][bj+1];
    float dz = sAI[ai+2] - sAJ[k][bj+2];
    float d = sqrtf(dx*dx + dy*dy + dz*dz + 1e-6f);
    float A  = d*d*(-0.92332483f);
    float Bc = d*1.84664966f;
    unsigned u[8];
    #pragma unroll
    for (int h = 0; h < 8; ++h){
      float mu0 = 2.f + (2*h  )*(4.f/3.f);
      float mu1 = 2.f + (2*h+1)*(4.f/3.f);
      float e0 = __builtin_amdgcn_exp2f(fmaf(Bc, mu0, A + (-0.92332483f*mu0*mu0)));
      float e1 = __builtin_amdgcn_exp2f(fmaf(Bc, mu1, A + (-0.92332483f*mu1*mu1)));
      u[h] = cvt_pk(e0, e1);
    }
    *(uint4*)&As[k*ASTR + 16  + p*8] = make_uint4(u[0], u[1], u[2], u[3]);
    *(uint4*)&As[k*ASTR + 216 + p*8] = make_uint4(u[4], u[5], u[6], u[7]);
  };

  rbf_task(tid);
  if (tid >= 274) rbf_task(tid + 238);   // tasks 512..749

  if (w == 1 && l < KNB){                // positional encoding body
    int k = l;
    ushort_t* row = &As[k*ASTR];
    float ch = sAJ[k][16];
    int off  = (int)sAJ[k][18];
    int dpos = off + 32;
    dpos = dpos < 0 ? 0 : (dpos > 64 ? 64 : dpos);
    if (!(ch > 0.5f)) dpos = 65;
    const float4* wp4 = (const float4*)(Wp + dpos*16);
    const float4* bp4 = (const float4*)bp;
    unsigned u[8];
    #pragma unroll
    for (int h = 0; h < 4; ++h){
      float4 wv = wp4[h], bv = bp4[h];
      u[2*h]   = cvt_pk(wv.x + bv.x, wv.y + bv.y);
      u[2*h+1] = cvt_pk(wv.z + bv.z, wv.w + bv.w);
    }
    *(uint4*)&row[0] = make_uint4(u[0], u[1], u[2], u[3]);
    *(uint4*)&row[8] = make_uint4(u[4], u[5], u[6], u[7]);
    *(unsigned*)&row[432] = cvt_pk(ch, sAJ[k][17]);
  } else if (w == 2 && l < KNB){         // quaternion body (qj in regs)
    int k = l;
    ushort_t* row = &As[k*ASTR];
    float R[3][3];
    R[0][0] = sQi[0]*qj0 + sQi[3]*qj3 + sQi[6]*qj6;
    R[0][1] = sQi[0]*qj1 + sQi[3]*qj4 + sQi[6]*qj7;
    R[0][2] = sQi[0]*qj2 + sQi[3]*qj5 + sQi[6]*qj8;
    R[1][0] = sQi[1]*qj0 + sQi[4]*qj3 + sQi[7]*qj6;
    R[1][1] = sQi[1]*qj1 + sQi[4]*qj4 + sQi[7]*qj7;
    R[1][2] = sQi[1]*qj2 + sQi[4]*qj5 + sQi[7]*qj8;
    R[2][0] = sQi[2]*qj0 + sQi[5]*qj3 + sQi[8]*qj6;
    R[2][1] = sQi[2]*qj1 + sQi[5]*qj4 + sQi[8]*qj7;
    R[2][2] = sQi[2]*qj2 + sQi[5]*qj5 + sQi[8]*qj8;
    float Rxx = R[0][0], Ryy = R[1][1], Rzz = R[2][2];
    float mx = 0.5f*sqrtf(fabsf(1.f + Rxx - Ryy - Rzz));
    float my = 0.5f*sqrtf(fabsf(1.f - Rxx + Ryy - Rzz));
    float mz = 0.5f*sqrtf(fabsf(1.f - Rxx - Ryy + Rzz));
    float qx = fsign(R[2][1] - R[1][2]) * mx;
    float qy = fsign(R[0][2] - R[2][0]) * my;
    float qz = fsign(R[1][0] - R[0][1]) * mz;
    float qw = sqrtf(fmaxf(1.f + Rxx + Ryy + Rzz, 0.f)) * 0.5f;
    float qn2 = qx*qx + qy*qy + qz*qz + qw*qw;
    float inv = qn2 > 0.f ? __builtin_amdgcn_rsqf(qn2) : 0.f;
    *(uint2*)&row[428] = make_uint2(cvt_pk(qx*inv, qy*inv), cvt_pk(qz*inv, qw*inv));
  } else if (w == 3 && l < KNB){         // E_direct body
    int k = l;
    ushort_t* row = &As[k*ASTR];
    float nx = sAI[0], ny = sAI[1], nz = sAI[2];
    const int amap[4] = {3, 0, 6, 9};
    float f[12];
    #pragma unroll
    for (int a = 0; a < 4; ++a){
      float dx = sAJ[k][amap[a]+0] - nx;
      float dy = sAJ[k][amap[a]+1] - ny;
      float dz = sAJ[k][amap[a]+2] - nz;
      float e0 = sQi[0]*dx + sQi[1]*dy + sQi[2]*dz;
      float e1 = sQi[3]*dx + sQi[4]*dy + sQi[5]*dz;
      float e2 = sQi[6]*dx + sQi[7]*dy + sQi[8]*dz;
      float ss = e0*e0 + e1*e1 + e2*e2;
      float inv = ss > 0.f ? __builtin_amdgcn_rsqf(ss) : 0.f;
      f[a*3+0] = e0*inv; f[a*3+1] = e1*inv; f[a*3+2] = e2*inv;
    }
    unsigned u[6];
    #pragma unroll
    for (int h = 0; h < 6; ++h) u[h] = cvt_pk(f[2*h], f[2*h+1]);
    *(uint4*)&row[416] = make_uint4(u[0], u[1], u[2], u[3]);
    *(uint2*)&row[424] = make_uint2(u[4], u[5]);
  }
  __syncthreads();

  // ---- Phase B: MFMA. wave w owns n-tile w, both m-tiles ----
  int aOff0 = (l & 15)*ASTR + (l >> 4)*8;
  int aOff1 = aOff0 + 16*ASTR;
  const ushort_t* bpw = Wfrag + ((size_t)(w*KST)*64 + l)*8;

  f32x4 acc0 = {0.f,0.f,0.f,0.f}, acc1 = acc0;

  bf16x8 a0 = *(const bf16x8*)&As[aOff0];
  bf16x8 a1 = *(const bf16x8*)&As[aOff1];
  bf16x8 b0 = *(const bf16x8*)bpw;
  #pragma unroll
  for (int s = 0; s < KST; ++s){
    bf16x8 a0n, a1n, b0n;
    if (s < KST-1){
      int ka = (s+1)*32;
      a0n = *(const bf16x8*)&As[aOff0 + ka];
      a1n = *(const bf16x8*)&As[aOff1 + ka];
      b0n = *(const bf16x8*)(bpw + (size_t)(s+1)*64*8);
    }
    acc0 = __builtin_amdgcn_mfma_f32_16x16x32_bf16(a0, b0, acc0, 0, 0, 0);
    acc1 = __builtin_amdgcn_mfma_f32_16x16x32_bf16(a1, b0, acc1, 0, 0, 0);
    if (s < KST-1){ a0 = a0n; a1 = a1n; b0 = b0n; }
  }
  __syncthreads();   // all As reads done; reuse as C tile

  float* Cs = (float*)As;       // [32][CSTR]
  int ccol = l & 15, crow = (l >> 4)*4;
  #pragma unroll
  for (int r = 0; r < 4; ++r){
    Cs[(crow + r)*CSTR      + w*16 + ccol] = acc0[r];
    Cs[(16 + crow + r)*CSTR + w*16 + ccol] = acc1[r];
  }
  __syncthreads();

  // ---- LayerNorm: 16 threads per edge row, 8 channels each ----
  if (tid < KNB*16){
    int row = tid >> 4, g = tid & 15;
    const float4* vr = (const float4*)&Cs[row*CSTR + g*8];
    float4 v0 = vr[0], v1 = vr[1];
    float v[8] = {v0.x,v0.y,v0.z,v0.w, v1.x,v1.y,v1.z,v1.w};
    float s = 0.f;
    #pragma unroll
    for (int c = 0; c < 8; ++c) s += v[c];
    #pragma unroll
    for (int off = 1; off < 16; off <<= 1) s += __shfl_xor(s, off, 16);
    float mu = s * (1.f/128.f);
    float vs = 0.f;
    #pragma unroll
    for (int c = 0; c < 8; ++c){ float dd = v[c] - mu; vs += dd*dd; }
    #pragma unroll
    for (int off = 1; off < 16; off <<= 1) vs += __shfl_xor(vs, off, 16);
    float inv = 1.f / sqrtf(vs * (1.f/128.f) + 1e-5f);
    const float4* g4 = (const float4*)&ge[g*8];
    const float4* b4 = (const float4*)&be[g*8];
    float4 ga = g4[0], gb = g4[1], ba = b4[0], bb = b4[1];
    float4 o0, o1;
    o0.x = (v[0]-mu)*inv*ga.x + ba.x;  o0.y = (v[1]-mu)*inv*ga.y + ba.y;
    o0.z = (v[2]-mu)*inv*ga.z + ba.z;  o0.w = (v[3]-mu)*inv*ga.w + ba.w;
    o1.x = (v[4]-mu)*inv*gb.x + bb.x;  o1.y = (v[5]-mu)*inv*gb.y + bb.y;
    o1.z = (v[6]-mu)*inv*gb.z + bb.z;  o1.w = (v[7]-mu)*inv*gb.w + bb.w;
    float4* dst = (float4*)&outE[((size_t)bi*KNB + row)*CH + g*8];
    dst[0] = o0;
    dst[1] = o1;
  }
}

extern "C" void kernel_launch(void* const* d_in, const int* in_sizes, int n_in,
                              void* d_out, int out_size, void* d_ws, size_t ws_size,
                              hipStream_t stream)
{
  const float* X    = (const float*)d_in[0];
  const float* mask = (const float*)d_in[1];
  const int*   resi = (const int*)  d_in[2];
  const int*   chn  = (const int*)  d_in[3];
  const float* Wp   = (const float*)d_in[4];
  const float* bp   = (const float*)d_in[5];
  const float* We   = (const float*)d_in[6];
  const float* Wn   = (const float*)d_in[7];
  const float* ge   = (const float*)d_in[8];
  const float* be   = (const float*)d_in[9];
  const float* gn   = (const float*)d_in[10];
  const float* bn   = (const float*)d_in[11];

  float* outV = (float*)d_out;                          // (4,1024,128)
  float* outE = outV + (size_t)BATCH*LEN*CH;            // (4,1024,30,128)
  float* outI = outE + (size_t)BATCH*LEN*KNB*CH;        // (4,1024,30) as float

  float* ws   = (float*)d_ws;
  float* wCb  = ws;                                     // 4096*4
  float* wQ   = wCb + (size_t)BATCH*LEN*4;              // 4096*12
  float* wVn  = wQ  + (size_t)BATCH*LEN*12;             // 4096*22
  int*   wIdx = (int*)(wVn + (size_t)BATCH*LEN*22);     // 4096*30
  float* wCa  = (float*)(wIdx + (size_t)BATCH*LEN*KNB); // 4096*4
  ushort_t* Wfrag = (ushort_t*)(wCa + (size_t)BATCH*LEN*4);  // 8*14*64*8 bf16

  prep_kernel<<<16 + 28, 256, 0, stream>>>(X, mask, We, wCb, wQ, wVn, wCa, Wfrag);
  topk_kernel<<<BATCH*LEN/4, 256, 0, stream>>>(wCa, wIdx);
  edge_kernel<<<BATCH*LEN, 512, 0, stream>>>(X, mask, resi, chn, Wp, bp, ge, be,
                                             wCb, wQ, wIdx, wVn, Wn, gn, bn, Wfrag,
                                             outV, outE, outI);
}

// Round 10
// 154.993 us; speedup vs baseline: 1.0147x; 1.0147x over previous
//
#include <hip/hip_runtime.h>

#define BATCH 4
#define LEN   1024
#define KNB   30
#define CH    128
#define EIN   434
#define KP    448      // padded K
#define KST   14       // k-steps of 32
#define ASTR  456      // A row stride in ushorts (228 words = 4 mod 32 banks)
#define CSTR  132      // C row stride in floats
#define AJS   20       // sAJ row stride in floats
#define NTB   44       // non-topk blocks in front_kernel (16 prep + 28 Wfrag)

typedef unsigned short ushort_t;
typedef __attribute__((ext_vector_type(8))) short bf16x8;
typedef __attribute__((ext_vector_type(4))) float f32x4;

// PAIRS atom indices: N=0, Ca=1, C=2, O=3, Cb=4
__constant__ int c_pa[24] = {0,2,3,4,1,1,1,1,0,0,0,4,4,3,0,2,3,4,2,3,4,2,3,2};
__constant__ int c_pb[24] = {0,2,3,4,0,2,3,4,2,3,4,2,3,2,1,1,1,1,0,0,0,4,4,3};

struct F3 { float x, y, z; };
__device__ __forceinline__ F3 f3sub(F3 a, F3 b){ return {a.x-b.x, a.y-b.y, a.z-b.z}; }
__device__ __forceinline__ F3 f3cross(F3 a, F3 b){
  return {a.y*b.z - a.z*b.y, a.z*b.x - a.x*b.z, a.x*b.y - a.y*b.x};
}
__device__ __forceinline__ float f3dot(F3 a, F3 b){ return a.x*b.x + a.y*b.y + a.z*b.z; }
__device__ __forceinline__ F3 f3norm(F3 a){
  float s2 = f3dot(a,a);
  float inv = (s2 > 0.f) ? __builtin_amdgcn_rsqf(s2) : 0.f;
  return {a.x*inv, a.y*inv, a.z*inv};
}
__device__ __forceinline__ float fsign(float x){ return (x > 0.f) ? 1.f : ((x < 0.f) ? -1.f : 0.f); }
__device__ __forceinline__ float clip1(float c){ return fminf(fmaxf(c, -1.f + 1e-7f), 1.f - 1e-7f); }

// cos(sign*acos(cd)) = cd ; sin(sign*acos(cd)) = sign*sqrt(1-cd^2)
__device__ __forceinline__ void dihedral_cs(F3 ua, F3 ub, F3 uc, float& c, float& s){
  F3 n0 = f3norm(f3cross(ua, ub));
  F3 n1 = f3norm(f3cross(ub, uc));
  float cd = clip1(f3dot(n0, n1));
  F3 v = f3norm(f3cross(n0, n1));
  c = cd;
  s = fsign(-f3dot(v, ub)) * sqrtf(1.f - cd*cd);
}

__device__ __forceinline__ ushort_t f2bf(float f){
  unsigned u = __float_as_uint(f);
  unsigned r = u + 0x7FFFu + ((u >> 16) & 1u);   // round-to-nearest-even
  return (ushort_t)(r >> 16);
}

// HW packed f32->bf16 (RNE): 1 inst per 2 elements
__device__ __forceinline__ unsigned cvt_pk(float a, float b){
  unsigned r;
  asm("v_cvt_pk_bf16_f32 %0, %1, %2" : "=v"(r) : "v"(a), "v"(b));
  return r;
}

// Column permutation: RBF pair p's 16 elems stored as two 8-halves at
// 16+p*8 and 216+p*8 (spreads phase-A b128 writes over all 8 bank-phases).
// Wfrag is packed with the same permutation so the GEMM is unchanged.
__device__ __forceinline__ int corig(int c){
  if (c < 16 || c >= 416) return c;
  int base = (c < 216) ? 16 : 216;
  int p = (c - base) >> 3, m = (c - base) & 7;
  return 16 + p*16 + m + ((c < 216) ? 0 : 8);
}

// Wave-wide u32 min via DPP (short dependency chain, 3 insts/step).
#define DPP_MIN_STEP(v, ctrl) do{                                            \
    unsigned t_ = (unsigned)__builtin_amdgcn_update_dpp(                     \
        (int)0xFFFFFFFF, (int)(v), (ctrl), 0xF, 0xF, false);                 \
    (v) = t_ < (v) ? t_ : (v);                                               \
  } while(0)
__device__ __forceinline__ unsigned wave_min_u32(unsigned v){
  DPP_MIN_STEP(v, 0x111);   // row_shr:1
  DPP_MIN_STEP(v, 0x112);   // row_shr:2
  DPP_MIN_STEP(v, 0x114);   // row_shr:4
  DPP_MIN_STEP(v, 0x118);   // row_shr:8
  DPP_MIN_STEP(v, 0x142);   // row_bcast:15
  DPP_MIN_STEP(v, 0x143);   // row_bcast:31
  return (unsigned)__builtin_amdgcn_readlane((int)v, 63);
}

// ---------------------------------------------------------------------------
// Front kernel (one launch, no cross-block dependencies):
//   blocks 0..15   : per-node prep (Cb, frame Q) -> wCb, wQ
//   blocks 16..43  : pack W_edge into bf16 B-fragment order (corig perm)
//   blocks 44..1067: wave-per-node top-30 from X directly (+outI, wDn) and
//                    node LN (vn recomputed from X in-wave) -> outV
__global__ __launch_bounds__(256) void front_kernel(
    const float* __restrict__ X, const float* __restrict__ mask,
    const float* __restrict__ We, const float* __restrict__ Wn,
    const float* __restrict__ gn, const float* __restrict__ bn,
    float* __restrict__ wCb, float* __restrict__ wQ,
    float* __restrict__ wDn, int* __restrict__ wIdx,
    ushort_t* __restrict__ Wfrag,
    float* __restrict__ outI, float* __restrict__ outV)
{
  if (blockIdx.x >= NTB){
    // ---------------- top-30 + node LN (reads only X, mask, Wn, gn, bn) ----
    int wid = threadIdx.x >> 6, l = threadIdx.x & 63;
    int bi = (blockIdx.x - NTB)*4 + wid;
    int b  = bi >> 10;
    const float* Xb = X + (size_t)b * LEN * 12;
    float cix = X[(size_t)bi*12 + 3];
    float ciy = X[(size_t)bi*12 + 4];
    float ciz = X[(size_t)bi*12 + 5];

    unsigned D[16];
    #pragma unroll
    for (int t = 0; t < 16; ++t){
      int j = l + 64*t;
      const float* pj = Xb + (size_t)j*12;
      float cjx = pj[3];
      float2 cyz = *(const float2*)(pj + 4);
      float dx = cix - cjx, dy = ciy - cyz.x, dz = ciz - cyz.y;
      D[t] = __float_as_uint(sqrtf(dx*dx + dy*dy + dz*dz + 1e-6f));
    }
    unsigned lmin = D[0]; unsigned jmin = (unsigned)l;
    #pragma unroll
    for (int t = 1; t < 16; ++t)
      if (D[t] < lmin){ lmin = D[t]; jmin = (unsigned)(l + 64*t); }

    for (int k = 0; k < KNB; ++k){
      unsigned dmin = wave_min_u32(lmin);
      unsigned long long tie = __ballot(lmin == dmin);
      bool iwin;
      unsigned jw;
      if (__popcll(tie) == 1ull){
        iwin = (lmin == dmin);         // unique dist -> that lane's jmin wins
        jw = jmin;
      } else {
        unsigned cand = (lmin == dmin) ? jmin : 0xFFFFFFFFu;
        jw = wave_min_u32(cand);       // min index among tied lanes
        iwin = (cand == jw);
      }
      if (iwin){
        wIdx[bi*KNB + k] = (int)jw;
        wDn[bi*KNB + k]  = __uint_as_float(dmin);
        outI[(size_t)bi*KNB + k] = (float)jw;
        int tw = (int)(jw >> 6);
        #pragma unroll
        for (int t = 0; t < 16; ++t) if (t == tw) D[t] = 0xFFFFFFFFu;
        lmin = D[0]; jmin = (unsigned)l;
        #pragma unroll
        for (int t = 1; t < 16; ++t)
          if (D[t] < lmin){ lmin = D[t]; jmin = (unsigned)(l + 64*t); }
      }
    }

    // ---- vn recompute (all lanes, broadcast loads) + LN fold -> outV ----
    int n = bi & (LEN - 1);
    const float* p = X + (size_t)bi * 12;
    const float4* p4 = (const float4*)p;
    float4 q0 = p4[0], q1 = p4[1], q2 = p4[2];
    F3 Na = {q0.x, q0.y, q0.z};
    F3 Ca = {q0.w, q1.x, q1.y};
    F3 Cc = {q1.z, q1.w, q2.x};
    F3 Oa = {q2.y, q2.z, q2.w};
    F3 bv = f3sub(Ca, Na);
    F3 cv = f3sub(Cc, Ca);
    F3 u0 = f3norm(bv);
    F3 u1 = f3norm(cv);
    float Q[9];
    if (n < LEN - 1){
      F3 b1 = f3norm(f3sub(u0, u1));
      F3 n0 = f3norm(f3cross(u0, u1));
      F3 r2 = f3cross(b1, n0);
      Q[0]=b1.x; Q[1]=b1.y; Q[2]=b1.z;
      Q[3]=n0.x; Q[4]=n0.y; Q[5]=n0.z;
      Q[6]=r2.x; Q[7]=r2.y; Q[8]=r2.z;
    } else {
      #pragma unroll
      for (int t = 0; t < 9; ++t) Q[t] = 0.f;
    }
    float m = mask[bi];
    bool hp = (n > 0), hn = (n < LEN - 1);
    F3 um1 = {0,0,0}, u2 = {0,0,0}, u3 = {0,0,0};
    if (hp){
      const float* pp = p - 12;
      F3 Cp = {pp[6], pp[7], pp[8]};
      um1 = f3norm(f3sub(Na, Cp));
    }
    if (hn){
      const float* pn = p + 12;
      F3 Nn  = {pn[0], pn[1], pn[2]};
      F3 Can = {pn[3], pn[4], pn[5]};
      u2 = f3norm(f3sub(Nn, Cc));
      u3 = f3norm(f3sub(Can, Nn));
    }
    float cD0=1.f,sD0=0.f, cD1=1.f,sD1=0.f, cD2=1.f,sD2=0.f;
    float cA0=1.f,sA0=0.f, cA1=1.f,sA1=0.f, cA2=1.f,sA2=0.f;
    if (hp){
      dihedral_cs(um1, u0, u1, cD0, sD0);
      cA0 = clip1(f3dot(um1, u0)); sA0 = sqrtf(1.f - cA0*cA0);
    }
    if (hn){
      dihedral_cs(u0, u1, u2, cD1, sD1);
      dihedral_cs(u1, u2, u3, cD2, sD2);
      cA1 = clip1(f3dot(u0, u1)); sA1 = sqrtf(1.f - cA1*cA1);
      cA2 = clip1(f3dot(u1, u2)); sA2 = sqrtf(1.f - cA2*cA2);
    }
    float vn[22];
    vn[0] = cD0*m; vn[1] = cD1*m; vn[2]  = cD2*m;
    vn[3] = sD0*m; vn[4] = sD1*m; vn[5]  = sD2*m;
    vn[6] = cA0*m; vn[7] = cA1*m; vn[8]  = cA2*m;
    vn[9] = sA0*m; vn[10]= sA1*m; vn[11] = sA2*m;
    F3 dxs[3];
    dxs[0] = {0.f, 0.f, 0.f};
    dxs[1] = f3sub(Cc, Na);
    dxs[2] = f3sub(Oa, Na);
    #pragma unroll
    for (int a = 0; a < 3; ++a){
      F3 dv = dxs[a];
      F3 du = { Q[0]*dv.x + Q[1]*dv.y + Q[2]*dv.z,
                Q[3]*dv.x + Q[4]*dv.y + Q[5]*dv.z,
                Q[6]*dv.x + Q[7]*dv.y + Q[8]*dv.z };
      F3 dn = f3norm(du);
      vn[12 + a*3 + 0] = dn.x * m;
      vn[12 + a*3 + 1] = dn.y * m;
      vn[12 + a*3 + 2] = dn.z * m;
    }
    vn[21] = m;

    float x0 = 0.f, x1 = 0.f;
    #pragma unroll
    for (int r = 0; r < 22; ++r){
      float vr = vn[r];
      x0 = fmaf(vr, Wn[r*CH + l],      x0);
      x1 = fmaf(vr, Wn[r*CH + l + 64], x1);
    }
    float sum = x0 + x1;
    #pragma unroll
    for (int off = 1; off < 64; off <<= 1) sum += __shfl_xor(sum, off);
    float mu = sum * (1.f/128.f);
    float d0 = x0 - mu, d1 = x1 - mu;
    float vs = d0*d0 + d1*d1;
    #pragma unroll
    for (int off = 1; off < 64; off <<= 1) vs += __shfl_xor(vs, off);
    float inv = 1.f / sqrtf(vs * (1.f/128.f) + 1e-5f);
    outV[(size_t)bi*CH + l]      = d0*inv*gn[l]    + bn[l];
    outV[(size_t)bi*CH + l + 64] = d1*inv*gn[l+64] + bn[l+64];
    return;
  }

  if (blockIdx.x >= 16){
    // ---------------- W_edge bf16 fragment pack (corig perm) ----------------
    int f = (blockIdx.x - 16)*256 + threadIdx.x;
    if (f >= 8*KST*64) return;
    int t = f / (KST*64);
    int s = (f / 64) % KST;
    int l = f & 63;
    int n  = t*16 + (l & 15);
    int k0 = s*32 + (l >> 4)*8;
    ushort_t v[8];
    #pragma unroll
    for (int j = 0; j < 8; ++j){
      int k = k0 + j;
      v[j] = (k < EIN) ? f2bf(We[(size_t)corig(k)*CH + n]) : (ushort_t)0;
    }
    ulong2* dst = (ulong2*)(Wfrag + (size_t)f*8);
    *dst = *(ulong2*)v;
    return;
  }

  // ---------------- per-node prep: Cb + frame Q ----------------------------
  int idx = blockIdx.x * 256 + threadIdx.x;
  int n = idx & (LEN - 1);
  const float* p = X + (size_t)idx * 12;
  const float4* p4 = (const float4*)p;
  float4 q0 = p4[0], q1 = p4[1], q2 = p4[2];
  F3 Na = {q0.x, q0.y, q0.z};
  F3 Ca = {q0.w, q1.x, q1.y};
  F3 Cc = {q1.z, q1.w, q2.x};
  F3 bv = f3sub(Ca, Na);
  F3 cv = f3sub(Cc, Ca);
  F3 av = f3cross(bv, cv);
  ((float4*)wCb)[idx] = make_float4(
    -0.58273431f*av.x + 0.56802827f*bv.x - 0.54067466f*cv.x + Ca.x,
    -0.58273431f*av.y + 0.56802827f*bv.y - 0.54067466f*cv.y + Ca.y,
    -0.58273431f*av.z + 0.56802827f*bv.z - 0.54067466f*cv.z + Ca.z, 0.f);

  F3 u0 = f3norm(bv);
  F3 u1 = f3norm(cv);
  float Q[9];
  if (n < LEN - 1){
    F3 b1 = f3norm(f3sub(u0, u1));
    F3 n0 = f3norm(f3cross(u0, u1));
    F3 r2 = f3cross(b1, n0);
    Q[0]=b1.x; Q[1]=b1.y; Q[2]=b1.z;
    Q[3]=n0.x; Q[4]=n0.y; Q[5]=n0.z;
    Q[6]=r2.x; Q[7]=r2.y; Q[8]=r2.z;
  } else {
    #pragma unroll
    for (int t = 0; t < 9; ++t) Q[t] = 0.f;
  }
  float4* wq4 = (float4*)(wQ + (size_t)idx*12);
  wq4[0] = make_float4(Q[0], Q[1], Q[2], Q[3]);
  wq4[1] = make_float4(Q[4], Q[5], Q[6], Q[7]);
  wq4[2] = make_float4(Q[8], 0.f, 0.f, 0.f);
}

// ---------------------------------------------------------------------------
// Block per node, 512 threads / 8 waves (round-7 structure, unchanged:
// wave w owns n-tile w for both m-tiles; B streamed with 1-deep prefetch).
__global__ __launch_bounds__(512) void edge_kernel(
    const float* __restrict__ X, const float* __restrict__ mask,
    const int* __restrict__ resi, const int* __restrict__ chain,
    const float* __restrict__ Wp, const float* __restrict__ bp,
    const float* __restrict__ ge, const float* __restrict__ be,
    const float* __restrict__ wCb, const float* __restrict__ wQ,
    const float* __restrict__ wDn, const int* __restrict__ wIdx,
    const ushort_t* __restrict__ Wfrag,
    float* __restrict__ outE)
{
  __shared__ __align__(16) ushort_t As[32*ASTR];   // 29184 B, reused as C (f32) later
  // sAJ row: [0..11]=X_j (N,Ca,C,O), [12..14]=Cb_j, [15]=Dn, [16]=chain,
  //          [17]=maskJ, [18]=offI(as float), [19]=pad.
  __shared__ __align__(16) float sAJ[KNB][AJS];
  __shared__ __align__(16) float sAI[16];
  __shared__ __align__(16) float sQi[12];

  int bi  = blockIdx.x;
  int b   = bi >> 10;
  int tid = threadIdx.x;
  int w   = tid >> 6, l = tid & 63;

  // ---- gather, spread across waves 0..3 ----
  float qj0=0.f,qj1=0.f,qj2=0.f,qj3=0.f,qj4=0.f,qj5=0.f,qj6=0.f,qj7=0.f,qj8=0.f;
  if (w == 0 && l < KNB){
    int j  = wIdx[bi*KNB + l];
    int gj = (b << 10) + j;
    const float4* pj4 = (const float4*)(X + (size_t)gj * 12);
    *(float4*)&sAJ[l][0] = pj4[0];
    *(float4*)&sAJ[l][4] = pj4[1];
    *(float4*)&sAJ[l][8] = pj4[2];
  } else if (w == 1 && l < KNB){
    int j  = wIdx[bi*KNB + l];
    int gj = (b << 10) + j;
    *(float4*)&sAJ[l][12] = ((const float4*)wCb)[gj];
    sAJ[l][15] = wDn[bi*KNB + l];
    sAJ[l][16] = (chain[bi] == chain[gj]) ? 1.f : 0.f;
    sAJ[l][17] = mask[gj];
    sAJ[l][18] = (float)(resi[bi] - resi[gj]);
  } else if (w == 2 && l < KNB){
    int j  = wIdx[bi*KNB + l];
    int gj = (b << 10) + j;
    const float4* q4 = (const float4*)(wQ + (size_t)gj * 12);
    float4 a = q4[0], bq = q4[1], cq = q4[2];
    qj0=a.x; qj1=a.y; qj2=a.z; qj3=a.w;
    qj4=bq.x; qj5=bq.y; qj6=bq.z; qj7=bq.w;
    qj8=cq.x;
  } else if (w == 3 && l == 0){
    const float4* pi4 = (const float4*)(X + (size_t)bi * 12);
    *(float4*)&sAI[0]  = pi4[0];
    *(float4*)&sAI[4]  = pi4[1];
    *(float4*)&sAI[8]  = pi4[2];
    *(float4*)&sAI[12] = ((const float4*)wCb)[bi];
  } else if (w == 3 && l == 1){
    const float4* q4 = (const float4*)(wQ + (size_t)bi * 12);
    *(float4*)&sQi[0] = q4[0];
    *(float4*)&sQi[4] = q4[1];
    *(float4*)&sQi[8] = q4[2];
  }
  // zero pad cols 434..447 of rows 0..29
  for (int e = tid; e < KNB*14; e += 512){
    int r = e / 14, c = EIN + (e % 14);
    As[r*ASTR + c] = 0;
  }
  __syncthreads();

  // ---- Phase A ----
  auto rbf_task = [&](int tau){
    int k = (int)(((unsigned)tau * 5243u) >> 17);   // tau/25
    int p = tau - k*25;
    float d;
    if (p == 0) d = sAJ[k][15];
    else {
      int ai = c_pa[p-1]*3, bj = c_pb[p-1]*3;
      float dx = sAI[ai+0] - sAJ[k][bj+0];
      float dy = sAI[ai+1] - sAJ[k][bj+1];
      float dz = sAI[ai+2] - sAJ[k][bj+2];
      d = sqrtf(dx*dx + dy*dy + dz*dz + 1e-6f);
    }
    float A  = d*d*(-0.92332483f);
    float Bc = d*1.84664966f;
    unsigned u[8];
    #pragma unroll
    for (int h = 0; h < 8; ++h){
      float mu0 = 2.f + (2*h  )*(4.f/3.f);
      float mu1 = 2.f + (2*h+1)*(4.f/3.f);
      float e0 = __builtin_amdgcn_exp2f(fmaf(Bc, mu0, A + (-0.92332483f*mu0*mu0)));
      float e1 = __builtin_amdgcn_exp2f(fmaf(Bc, mu1, A + (-0.92332483f*mu1*mu1)));
      u[h] = cvt_pk(e0, e1);
    }
    *(uint4*)&As[k*ASTR + 16  + p*8] = make_uint4(u[0], u[1], u[2], u[3]);
    *(uint4*)&As[k*ASTR + 216 + p*8] = make_uint4(u[4], u[5], u[6], u[7]);
  };

  rbf_task(tid);
  if (tid >= 274) rbf_task(tid + 238);   // tasks 512..749

  if (w == 1 && l < KNB){                // positional encoding body
    int k = l;
    ushort_t* row = &As[k*ASTR];
    float ch = sAJ[k][16];
    int off  = (int)sAJ[k][18];
    int dpos = off + 32;
    dpos = dpos < 0 ? 0 : (dpos > 64 ? 64 : dpos);
    if (!(ch > 0.5f)) dpos = 65;
    const float4* wp4 = (const float4*)(Wp + dpos*16);
    const float4* bp4 = (const float4*)bp;
    unsigned u[8];
    #pragma unroll
    for (int h = 0; h < 4; ++h){
      float4 wv = wp4[h], bv = bp4[h];
      u[2*h]   = cvt_pk(wv.x + bv.x, wv.y + bv.y);
      u[2*h+1] = cvt_pk(wv.z + bv.z, wv.w + bv.w);
    }
    *(uint4*)&row[0] = make_uint4(u[0], u[1], u[2], u[3]);
    *(uint4*)&row[8] = make_uint4(u[4], u[5], u[6], u[7]);
    *(unsigned*)&row[432] = cvt_pk(ch, sAJ[k][17]);
  } else if (w == 2 && l < KNB){         // quaternion body (qj in regs)
    int k = l;
    ushort_t* row = &As[k*ASTR];
    float R[3][3];
    R[0][0] = sQi[0]*qj0 + sQi[3]*qj3 + sQi[6]*qj6;
    R[0][1] = sQi[0]*qj1 + sQi[3]*qj4 + sQi[6]*qj7;
    R[0][2] = sQi[0]*qj2 + sQi[3]*qj5 + sQi[6]*qj8;
    R[1][0] = sQi[1]*qj0 + sQi[4]*qj3 + sQi[7]*qj6;
    R[1][1] = sQi[1]*qj1 + sQi[4]*qj4 + sQi[7]*qj7;
    R[1][2] = sQi[1]*qj2 + sQi[4]*qj5 + sQi[7]*qj8;
    R[2][0] = sQi[2]*qj0 + sQi[5]*qj3 + sQi[8]*qj6;
    R[2][1] = sQi[2]*qj1 + sQi[5]*qj4 + sQi[8]*qj7;
    R[2][2] = sQi[2]*qj2 + sQi[5]*qj5 + sQi[8]*qj8;
    float Rxx = R[0][0], Ryy = R[1][1], Rzz = R[2][2];
    float mx = 0.5f*sqrtf(fabsf(1.f + Rxx - Ryy - Rzz));
    float my = 0.5f*sqrtf(fabsf(1.f - Rxx + Ryy - Rzz));
    float mz = 0.5f*sqrtf(fabsf(1.f - Rxx - Ryy + Rzz));
    float qx = fsign(R[2][1] - R[1][2]) * mx;
    float qy = fsign(R[0][2] - R[2][0]) * my;
    float qz = fsign(R[1][0] - R[0][1]) * mz;
    float qw = sqrtf(fmaxf(1.f + Rxx + Ryy + Rzz, 0.f)) * 0.5f;
    float qn2 = qx*qx + qy*qy + qz*qz + qw*qw;
    float inv = qn2 > 0.f ? __builtin_amdgcn_rsqf(qn2) : 0.f;
    *(uint2*)&row[428] = make_uint2(cvt_pk(qx*inv, qy*inv), cvt_pk(qz*inv, qw*inv));
  } else if (w == 3 && l < KNB){         // E_direct body
    int k = l;
    ushort_t* row = &As[k*ASTR];
    float nx = sAI[0], ny = sAI[1], nz = sAI[2];
    const int amap[4] = {3, 0, 6, 9};
    float f[12];
    #pragma unroll
    for (int a = 0; a < 4; ++a){
      float dx = sAJ[k][amap[a]+0] - nx;
      float dy = sAJ[k][amap[a]+1] - ny;
      float dz = sAJ[k][amap[a]+2] - nz;
      float e0 = sQi[0]*dx + sQi[1]*dy + sQi[2]*dz;
      float e1 = sQi[3]*dx + sQi[4]*dy + sQi[5]*dz;
      float e2 = sQi[6]*dx + sQi[7]*dy + sQi[8]*dz;
      float ss = e0*e0 + e1*e1 + e2*e2;
      float inv = ss > 0.f ? __builtin_amdgcn_rsqf(ss) : 0.f;
      f[a*3+0] = e0*inv; f[a*3+1] = e1*inv; f[a*3+2] = e2*inv;
    }
    unsigned u[6];
    #pragma unroll
    for (int h = 0; h < 6; ++h) u[h] = cvt_pk(f[2*h], f[2*h+1]);
    *(uint4*)&row[416] = make_uint4(u[0], u[1], u[2], u[3]);
    *(uint2*)&row[424] = make_uint2(u[4], u[5]);
  }
  __syncthreads();

  // ---- Phase B: MFMA. wave w owns n-tile w, both m-tiles ----
  int aOff0 = (l & 15)*ASTR + (l >> 4)*8;
  int aOff1 = aOff0 + 16*ASTR;
  const ushort_t* bpw = Wfrag + ((size_t)(w*KST)*64 + l)*8;

  f32x4 acc0 = {0.f,0.f,0.f,0.f}, acc1 = acc0;

  bf16x8 a0 = *(const bf16x8*)&As[aOff0];
  bf16x8 a1 = *(const bf16x8*)&As[aOff1];
  bf16x8 b0 = *(const bf16x8*)bpw;
  #pragma unroll
  for (int s = 0; s < KST; ++s){
    bf16x8 a0n, a1n, b0n;
    if (s < KST-1){
      int ka = (s+1)*32;
      a0n = *(const bf16x8*)&As[aOff0 + ka];
      a1n = *(const bf16x8*)&As[aOff1 + ka];
      b0n = *(const bf16x8*)(bpw + (size_t)(s+1)*64*8);
    }
    acc0 = __builtin_amdgcn_mfma_f32_16x16x32_bf16(a0, b0, acc0, 0, 0, 0);
    acc1 = __builtin_amdgcn_mfma_f32_16x16x32_bf16(a1, b0, acc1, 0, 0, 0);
    if (s < KST-1){ a0 = a0n; a1 = a1n; b0 = b0n; }
  }
  __syncthreads();   // all As reads done; reuse as C tile

  float* Cs = (float*)As;       // [32][CSTR]
  int ccol = l & 15, crow = (l >> 4)*4;
  #pragma unroll
  for (int r = 0; r < 4; ++r){
    Cs[(crow + r)*CSTR      + w*16 + ccol] = acc0[r];
    Cs[(16 + crow + r)*CSTR + w*16 + ccol] = acc1[r];
  }
  __syncthreads();

  // ---- LayerNorm: 16 threads per edge row, 8 channels each ----
  if (tid < KNB*16){
    int row = tid >> 4, g = tid & 15;
    const float4* vr = (const float4*)&Cs[row*CSTR + g*8];
    float4 v0 = vr[0], v1 = vr[1];
    float v[8] = {v0.x,v0.y,v0.z,v0.w, v1.x,v1.y,v1.z,v1.w};
    float s = 0.f;
    #pragma unroll
    for (int c = 0; c < 8; ++c) s += v[c];
    #pragma unroll
    for (int off = 1; off < 16; off <<= 1) s += __shfl_xor(s, off, 16);
    float mu = s * (1.f/128.f);
    float vs = 0.f;
    #pragma unroll
    for (int c = 0; c < 8; ++c){ float dd = v[c] - mu; vs += dd*dd; }
    #pragma unroll
    for (int off = 1; off < 16; off <<= 1) vs += __shfl_xor(vs, off, 16);
    float inv = 1.f / sqrtf(vs * (1.f/128.f) + 1e-5f);
    const float4* g4 = (const float4*)&ge[g*8];
    const float4* b4 = (const float4*)&be[g*8];
    float4 ga = g4[0], gb = g4[1], ba = b4[0], bb = b4[1];
    float4 o0, o1;
    o0.x = (v[0]-mu)*inv*ga.x + ba.x;  o0.y = (v[1]-mu)*inv*ga.y + ba.y;
    o0.z = (v[2]-mu)*inv*ga.z + ba.z;  o0.w = (v[3]-mu)*inv*ga.w + ba.w;
    o1.x = (v[4]-mu)*inv*gb.x + bb.x;  o1.y = (v[5]-mu)*inv*gb.y + bb.y;
    o1.z = (v[6]-mu)*inv*gb.z + bb.z;  o1.w = (v[7]-mu)*inv*gb.w + bb.w;
    float4* dst = (float4*)&outE[((size_t)bi*KNB + row)*CH + g*8];
    dst[0] = o0;
    dst[1] = o1;
  }
}

extern "C" void kernel_launch(void* const* d_in, const int* in_sizes, int n_in,
                              void* d_out, int out_size, void* d_ws, size_t ws_size,
                              hipStream_t stream)
{
  const float* X    = (const float*)d_in[0];
  const float* mask = (const float*)d_in[1];
  const int*   resi = (const int*)  d_in[2];
  const int*   chn  = (const int*)  d_in[3];
  const float* Wp   = (const float*)d_in[4];
  const float* bp   = (const float*)d_in[5];
  const float* We   = (const float*)d_in[6];
  const float* Wn   = (const float*)d_in[7];
  const float* ge   = (const float*)d_in[8];
  const float* be   = (const float*)d_in[9];
  const float* gn   = (const float*)d_in[10];
  const float* bn   = (const float*)d_in[11];

  float* outV = (float*)d_out;                          // (4,1024,128)
  float* outE = outV + (size_t)BATCH*LEN*CH;            // (4,1024,30,128)
  float* outI = outE + (size_t)BATCH*LEN*KNB*CH;        // (4,1024,30) as float

  float* ws   = (float*)d_ws;
  float* wCb  = ws;                                     // 4096*4
  float* wQ   = wCb + (size_t)BATCH*LEN*4;              // 4096*12
  float* wDn  = wQ  + (size_t)BATCH*LEN*12;             // 4096*30
  int*   wIdx = (int*)(wDn + (size_t)BATCH*LEN*KNB);    // 4096*30
  ushort_t* Wfrag = (ushort_t*)(wIdx + (size_t)BATCH*LEN*KNB);  // 8*14*64*8 bf16

  front_kernel<<<NTB + BATCH*LEN/4, 256, 0, stream>>>(
      X, mask, We, Wn, gn, bn, wCb, wQ, wDn, wIdx, Wfrag, outI, outV);
  edge_kernel<<<BATCH*LEN, 512, 0, stream>>>(X, mask, resi, chn, Wp, bp, ge, be,
                                             wCb, wQ, wDn, wIdx, Wfrag, outE);
}